// Round 8
// baseline (235.446 us; speedup 1.0000x reference)
//
#include <hip/hip_runtime.h>
#include <hip/hip_bf16.h>
#include <stdint.h>

// Problem: B=8192, E=1024, P=512. x:[8192,2048] f32, w:[1024,512] f32, b:[512] f32.
// out: scalar = mean_i( -S[i,i^4096]/T + log(sum_{j!=i} exp(S[i,j]/T)) ),
// S = zn zn^T (symmetric -> upper triangle of 128x128 blocks), T=0.1.
// Pipeline: prep (wt=bf16(w^T), sumexp=0) -> projnorm (fused relu-GEMM +
// row-norm + fp8 quant, barrier-light) -> gemm2 (fp8 MX, R6-proven) -> finalize.
// Flat-row identity: z[8192][1024] row r = [proj(x_flat[2r]) || proj(x_flat[2r+1])],
// so zn8 byte addr = f*512 + n for flat row f, col n.
//
// ws layout (bytes):
//   wt  bf16 [512][1024]    @ 0
//   zn8 fp8  [8192][1024]   @ 68157440
//   sumexp f32[8192]        @ 84934656
//   pos    f32[8192]        @ 84967424

typedef __attribute__((ext_vector_type(8))) __bf16 bf16x8;
typedef __attribute__((ext_vector_type(4))) float f32x4;
typedef __attribute__((ext_vector_type(4))) int i32x4;
typedef __attribute__((ext_vector_type(8))) int i32x8;

__device__ __forceinline__ unsigned short f2bf(float f) {
  union { float f; unsigned int u; } v; v.f = f;
  unsigned int u = v.u;
  u += 0x7FFFu + ((u >> 16) & 1u);
  return (unsigned short)(u >> 16);
}

// pack two relu'd f32 (trunc to bf16): low short = a, high short = b.
__device__ __forceinline__ unsigned int rpack(float a, float b) {
  return __builtin_amdgcn_perm(__float_as_uint(fmaxf(b, 0.f)),
                               __float_as_uint(fmaxf(a, 0.f)), 0x07060302u);
}

__device__ __forceinline__ bf16x8 pack8(float4 lo, float4 hi) {
  union { unsigned int i[4]; bf16x8 v; } u;
  u.i[0] = rpack(lo.x, lo.y);
  u.i[1] = rpack(lo.z, lo.w);
  u.i[2] = rpack(hi.x, hi.y);
  u.i[3] = rpack(hi.z, hi.w);
  return u.v;
}

// ---------------- prep: wt = bf16(w^T); sumexp = 0 ---------------------------
__global__ __launch_bounds__(256) void prep_kernel(
    const float* __restrict__ w, unsigned short* __restrict__ wt,
    float* __restrict__ sumexp) {
  int tid = blockIdx.x * 256 + threadIdx.x;      // 2048 blocks -> 524288
  int k = tid & 1023, n = tid >> 10;
  wt[(n << 10) + k] = f2bf(w[k * 512 + n]);
  if (tid < 8192) sumexp[tid] = 0.f;
}

// -------- projnorm: fused relu(x)@w+b, row-norm, fp8 quant -------------------
// Block: 32 flat rows x 512 N (full). 4 waves, wave w: n-range [w*128,+128).
// A-frags built in regs from x (relu + bf16-trunc pack); B-frags read directly
// from L2-resident wt (16B b128, 16 full lines/instr). No K-loop barriers.
// C/D 16x16: col = L&15, row = (L>>4)*4 + reg.
__global__ __launch_bounds__(256) void projnorm_kernel(
    const float* __restrict__ x, const unsigned short* __restrict__ wt,
    const float* __restrict__ bias, unsigned char* __restrict__ zn8) {
  int tid = threadIdx.x, L = tid & 63, w = tid >> 6;
  int l4 = L & 15, q = L >> 4;
  int i0 = blockIdx.x * 32;

  f32x4 acc[2][8];
#pragma unroll
  for (int mt = 0; mt < 2; ++mt)
#pragma unroll
    for (int nt = 0; nt < 8; ++nt) acc[mt][nt] = (f32x4)0.f;

  const float* A0 = x + (size_t)(i0 + l4) * 1024 + q * 8;
  const float* A1 = A0 + 16 * 1024;
  const unsigned short* B0 = wt + (size_t)(w * 128 + l4) * 1024 + q * 8;

#pragma unroll 2
  for (int k0 = 0; k0 < 1024; k0 += 32) {
    float4 lo0 = *(const float4*)(A0 + k0);
    float4 hi0 = *(const float4*)(A0 + k0 + 4);
    float4 lo1 = *(const float4*)(A1 + k0);
    float4 hi1 = *(const float4*)(A1 + k0 + 4);
    bf16x8 af0 = pack8(lo0, hi0);
    bf16x8 af1 = pack8(lo1, hi1);
#pragma unroll
    for (int nt = 0; nt < 8; ++nt) {
      bf16x8 bf = *(const bf16x8*)(B0 + nt * 16 * 1024 + k0);
      acc[0][nt] = __builtin_amdgcn_mfma_f32_16x16x32_bf16(af0, bf, acc[0][nt], 0, 0, 0);
      acc[1][nt] = __builtin_amdgcn_mfma_f32_16x16x32_bf16(af1, bf, acc[1][nt], 0, 0, 0);
    }
  }

  // epilogue: +bias, row sum-of-squares (full 1024-feature z-row = local flat
  // row pair), inv = 16/max(||z||,eps), fp8 quantize, write zn8[f*512+n].
  __shared__ float prt[4][32];
  __shared__ float sinv[32];
  float bn[8];
#pragma unroll
  for (int nt = 0; nt < 8; ++nt) bn[nt] = bias[w * 128 + nt * 16 + l4];
  float sp[2][4];
#pragma unroll
  for (int mt = 0; mt < 2; ++mt)
#pragma unroll
    for (int r = 0; r < 4; ++r) {
      float s = 0.f;
#pragma unroll
      for (int nt = 0; nt < 8; ++nt) {
        float v = acc[mt][nt][r] + bn[nt];
        acc[mt][nt][r] = v;
        s += v * v;
      }
      sp[mt][r] = s;
    }
#pragma unroll
  for (int mt = 0; mt < 2; ++mt)
#pragma unroll
    for (int r = 0; r < 4; ++r) {
      float v2 = sp[mt][r];
      v2 += __shfl_xor(v2, 1); v2 += __shfl_xor(v2, 2);
      v2 += __shfl_xor(v2, 4); v2 += __shfl_xor(v2, 8);
      sp[mt][r] = v2;
    }
  if (l4 == 0) {
#pragma unroll
    for (int mt = 0; mt < 2; ++mt)
#pragma unroll
      for (int r = 0; r < 4; ++r)
        prt[w][mt * 16 + q * 4 + r] = sp[mt][r];
  }
  __syncthreads();
  if (tid < 16) {
    float ssq = 0.f;
#pragma unroll
    for (int w2 = 0; w2 < 4; ++w2)
      ssq += prt[w2][2 * tid] + prt[w2][2 * tid + 1];
    float inv = 16.f / fmaxf(sqrtf(ssq), 1e-8f);
    sinv[2 * tid] = inv;
    sinv[2 * tid + 1] = inv;
  }
  __syncthreads();
#pragma unroll
  for (int mt = 0; mt < 2; ++mt)
#pragma unroll
    for (int r = 0; r < 4; ++r) {
      int fl = mt * 16 + q * 4 + r;
      float sc = sinv[fl];
      size_t base = (size_t)(i0 + fl) * 512 + w * 128 + l4;
#pragma unroll
      for (int nt = 0; nt < 8; ++nt) {
        float v = acc[mt][nt][r] * sc;
        int p = __builtin_amdgcn_cvt_pk_fp8_f32(v, v, 0, false);
        zn8[base + nt * 16] = (unsigned char)(p & 0xFF);
      }
    }
}

// -------- GEMM2 fp8 symmetric: 16x16x128 MX, 4x4 grid, BK=128 (R6-proven) ----
// LDS tile (16 KB), 4 panels of 256x16B units, XOR-swizzled positions
// p = u ^ ((u>>3)&7) (u = row*2 + h); staging realizes it via lane-side
// source permutation lp = L ^ ((L>>3)&7).
// A-frag lane L: m = L&15, k = (L>>4)*32 + j. C/D: col=L&15, row=(L>>4)*4+reg.
__global__ __launch_bounds__(256, 3) void gemm2_kernel(
    const unsigned char* __restrict__ zn8,
    float* __restrict__ sumexp, float* __restrict__ pos) {
  __shared__ unsigned char As[16384] __attribute__((aligned(16)));
  __shared__ unsigned char Bs[16384] __attribute__((aligned(16)));
  int rem = blockIdx.x, bi = 0;
  while (rem >= 64 - bi) { rem -= 64 - bi; ++bi; }
  int bj = bi + rem;
  bool diag = (bi == bj);
  int i0 = bi * 128, j0 = bj * 128;

  int tid = threadIdx.x, L = tid & 63, w = tid >> 6;
  int wm = w >> 1, wn = w & 1;
  int l4 = L & 15;
  int panel = (L >> 4) * 4096;

  // swizzled staging source: position P = w*64 + L  ->  u = w*64 + lp
  int lp = L ^ ((L >> 3) & 7);
  int srow = w * 32 + (lp >> 1), sh = lp & 1;

  f32x4 acc[4][4];
#pragma unroll
  for (int a = 0; a < 4; ++a)
#pragma unroll
    for (int bq = 0; bq < 4; ++bq) acc[a][bq] = (f32x4)0.f;

  const unsigned char* Ag = zn8 + (i0 + srow) * 1024 + sh * 16;
  const unsigned char* Bg = zn8 + (j0 + srow) * 1024 + sh * 16;
  const unsigned char* Bsrc = diag ? (const unsigned char*)As : (const unsigned char*)Bs;

#pragma unroll 1
  for (int k0 = 0; k0 < 1024; k0 += 128) {
    __syncthreads();
#pragma unroll
    for (int t = 0; t < 4; ++t)
      __builtin_amdgcn_global_load_lds(
          (const __attribute__((address_space(1))) void*)(Ag + k0 + t * 32),
          (__attribute__((address_space(3))) void*)(As + t * 4096 + (tid & ~63) * 16),
          16, 0, 0);
    if (!diag) {
#pragma unroll
      for (int t = 0; t < 4; ++t)
        __builtin_amdgcn_global_load_lds(
            (const __attribute__((address_space(1))) void*)(Bg + k0 + t * 32),
            (__attribute__((address_space(3))) void*)(Bs + t * 4096 + (tid & ~63) * 16),
            16, 0, 0);
    }
    __syncthreads();
    // preload A fragments (swizzled positions)
    i32x8 afr[4];
#pragma unroll
    for (int mt = 0; mt < 4; ++mt) {
      int row = wm * 64 + mt * 16 + l4;
      int p0 = (row * 2) ^ ((row >> 2) & 7);
      i32x4 lo = *(const i32x4*)(As + panel + p0 * 16);
      i32x4 hi = *(const i32x4*)(As + panel + (p0 ^ 1) * 16);
      afr[mt] = (i32x8){lo.x, lo.y, lo.z, lo.w, hi.x, hi.y, hi.z, hi.w};
    }
#pragma unroll
    for (int nt = 0; nt < 4; ++nt) {
      int row = wn * 64 + nt * 16 + l4;
      int p0 = (row * 2) ^ ((row >> 2) & 7);
      i32x4 lo = *(const i32x4*)(Bsrc + panel + p0 * 16);
      i32x4 hi = *(const i32x4*)(Bsrc + panel + (p0 ^ 1) * 16);
      i32x8 bfr = (i32x8){lo.x, lo.y, lo.z, lo.w, hi.x, hi.y, hi.z, hi.w};
#pragma unroll
      for (int mt = 0; mt < 4; ++mt)
        acc[mt][nt] = __builtin_amdgcn_mfma_scale_f32_16x16x128_f8f6f4(
            afr[mt], bfr, acc[mt][nt], 0, 0,
            0, 0x7F7F7F7F, 0, 0x7F7F7F7F);
    }
  }

  // epilogue (verified): s = acc*10/256; diag mask; pos; exp;
  // row-sums (lane bits 0-3) + col-sums (lane bits 4-5) -> atomics.
  const float SC = 10.0f / 256.0f;
  float rs[4][4];
  float cs[4] = {0.f, 0.f, 0.f, 0.f};
#pragma unroll
  for (int mt = 0; mt < 4; ++mt)
#pragma unroll
    for (int r = 0; r < 4; ++r) rs[mt][r] = 0.f;
  int ib = i0 + wm * 64 + ((L >> 4) << 2);
  int jb = j0 + wn * 64 + l4;
#pragma unroll
  for (int mt = 0; mt < 4; ++mt)
#pragma unroll
    for (int nt = 0; nt < 4; ++nt) {
      int j = jb + nt * 16;
#pragma unroll
      for (int r = 0; r < 4; ++r) {
        int i = ib + mt * 16 + r;
        float s = acc[mt][nt][r] * SC;
        if (j == (i ^ 4096)) { pos[i] = s; pos[j] = s; }
        float e = (i == j) ? 0.f : __expf(s);
        rs[mt][r] += e;
        if (!diag) cs[nt] += e;
      }
    }
#pragma unroll
  for (int mt = 0; mt < 4; ++mt)
#pragma unroll
    for (int r = 0; r < 4; ++r) {
      float v = rs[mt][r];
      v += __shfl_xor(v, 1); v += __shfl_xor(v, 2);
      v += __shfl_xor(v, 4); v += __shfl_xor(v, 8);
      rs[mt][r] = v;
    }
  int sel = l4;
  float myv = rs[0][0];
#pragma unroll
  for (int mt = 0; mt < 4; ++mt)
#pragma unroll
    for (int r = 0; r < 4; ++r)
      if (sel == mt * 4 + r) myv = rs[mt][r];
  int rowi = i0 + wm * 64 + (sel >> 2) * 16 + ((L >> 4) << 2) + (sel & 3);
  atomicAdd(&sumexp[rowi], myv);
  if (!diag) {
#pragma unroll
    for (int nt = 0; nt < 4; ++nt) {
      float v = cs[nt];
      v += __shfl_xor(v, 16); v += __shfl_xor(v, 32);
      if ((L >> 4) == 0) atomicAdd(&sumexp[jb + nt * 16], v);
    }
  }
}

// ---------------- finalize: out = mean(log(sumexp) - pos) --------------------
__global__ __launch_bounds__(1024) void finalize_kernel(
    const float* __restrict__ sumexp, const float* __restrict__ pos,
    float* __restrict__ out) {
  int t = threadIdx.x;
  float s = 0.f;
  for (int i = t; i < 8192; i += 1024) s += logf(sumexp[i]) - pos[i];
#pragma unroll
  for (int off = 1; off < 64; off <<= 1) s += __shfl_xor(s, off);
  __shared__ float red[16];
  if ((t & 63) == 0) red[t >> 6] = s;
  __syncthreads();
  if (t == 0) {
    float tot = 0.f;
    for (int k2 = 0; k2 < 16; ++k2) tot += red[k2];
    out[0] = tot * (1.0f / 8192.0f);
  }
}

extern "C" void kernel_launch(void* const* d_in, const int* in_sizes, int n_in,
                              void* d_out, int out_size, void* d_ws, size_t ws_size,
                              hipStream_t stream) {
  const float* x = (const float*)d_in[0];
  const float* w = (const float*)d_in[1];
  const float* b = (const float*)d_in[2];
  float* out = (float*)d_out;
  char* ws = (char*)d_ws;
  unsigned short* wt = (unsigned short*)(ws);
  unsigned char* zn8 = (unsigned char*)(ws + 68157440);
  float* sumexp      = (float*)(ws + 84934656);
  float* pos         = (float*)(ws + 84967424);

  prep_kernel<<<2048, 256, 0, stream>>>(w, wt, sumexp);
  projnorm_kernel<<<512, 256, 0, stream>>>(x, wt, b, zn8);
  gemm2_kernel<<<2080, 256, 0, stream>>>(zn8, sumexp, pos);
  finalize_kernel<<<1, 1024, 0, stream>>>(sumexp, pos, out);
}